// Round 1
// 252.099 us; speedup vs baseline: 1.0694x; 1.0694x over previous
//
#include <hip/hip_runtime.h>
#include <stdint.h>

#define TPB 512

constexpr int Bb   = 8;    // batch
constexpr int Vv   = 200;  // vertices
constexpr int Tt   = 128;  // time
constexpr int CIN  = 128;  // concat channels
constexpr int COUT = 64;   // K_HEADS * D_HEAD

typedef __attribute__((ext_vector_type(8))) short bf16x8;
typedef __attribute__((ext_vector_type(4))) short short4v;
typedef __attribute__((ext_vector_type(4))) float f32x4;

// bf16 helpers (manual RNE)
__device__ __forceinline__ unsigned short f2bf(float f) {
    union { float f; unsigned u; } x; x.f = f;
    unsigned r = x.u + 0x7fffu + ((x.u >> 16) & 1u);
    return (unsigned short)(r >> 16);
}
// pack two floats -> two bf16 in one u32 (low = a), RNE
__device__ __forceinline__ unsigned pk2(float a, float b) {
    return (unsigned)f2bf(a) | ((unsigned)f2bf(b) << 16);
}

// 16x16x16 bf16 MFMA (K=16): used for QK^T (K=8 real) and PV.
#if __has_builtin(__builtin_amdgcn_mfma_f32_16x16x16bf16_1k)
#define MFMA16(a, b, c) __builtin_amdgcn_mfma_f32_16x16x16bf16_1k(a, b, c, 0, 0, 0)
#else
__device__ __forceinline__ f32x4 mfma16_asm(short4v a, short4v b, f32x4 c) {
    f32x4 d;
    asm("v_mfma_f32_16x16x16_bf16 %0, %1, %2, %3" : "=v"(d) : "v"(a), "v"(b), "v"(c));
    return d;
}
#define MFMA16(a, b, c) mfma16_asm(a, b, c)
#endif

// ---- prep: convert W's to bf16 into d_ws (same work every launch) ----
// ws layout (ushort): [0,8192) Wq [8192,16384) Wk [16384,24576) Wv [24576,28672) Wo
__global__ void prep_w(const float* __restrict__ Wq, const float* __restrict__ Wk,
                       const float* __restrict__ Wv, const float* __restrict__ Wo,
                       unsigned short* __restrict__ ws) {
    int i = blockIdx.x * 256 + threadIdx.x;  // 28672 total
    float v;
    if (i < 8192)       v = Wq[i];
    else if (i < 16384) v = Wk[i - 8192];
    else if (i < 24576) v = Wv[i - 16384];
    else                v = Wo[i - 24576];
    ws[i] = f2bf(v);
}

// One block per (b, v). LDS 52 KiB -> 3 blocks/CU (was 64 KiB -> 2):
//   qk  bf16 Q[128][64] @0, K[128][64] @16384  (8B-chunk swizzle: phys_hc = hc ^ (t&14))
//   vt  bf16 VT[64 dg][128 s] @32768 (phase 1 + vfrag load)
//   ot  bf16 [128 t][64 i]    @32768 (overlays vt after vfrag barrier)
//   xt  bf16 [16 t][128 c]    @49152 (phase-1 staging, 8 rounds of 16 t)
__global__ __launch_bounds__(TPB, 6)
void tatt_fused(const float* __restrict__ x, const float* __restrict__ tem,
                const float* __restrict__ bq, const float* __restrict__ bk,
                const float* __restrict__ bv, const float* __restrict__ bo,
                const unsigned short* __restrict__ ws,
                float* __restrict__ out)
{
    __shared__ __align__(16) unsigned char smem[53248];
    unsigned short* qk = (unsigned short*)smem;            // Q @0 (elts), K @8192 (elts)
    unsigned short* vt = (unsigned short*)(smem + 32768);  // VT [64][128]
    unsigned short* ot = (unsigned short*)(smem + 32768);  // overlays vt (after barrier)
    unsigned short* xt = (unsigned short*)(smem + 49152);  // [16][128]

    const int tid = threadIdx.x;
    const int w = tid >> 6, lane = tid & 63;
    const int l15 = lane & 15, qd = lane >> 4;
    const int b = blockIdx.x / Vv, v = blockIdx.x % Vv;
    const float QS = 1.44269504088896f * 0.35355339059327f;  // log2(e)/sqrt(8)

    // ---------------- phase 1: QKV projection, 8 rounds of 16 t ----------------
    {
        // Coalesced loads: lane group = t (16 lanes x 4B = 64B segments),
        // thread owns 4 consecutive channels -> one ds_write_b64 per round.
        const int tl = tid & 15, cq = tid >> 4;
        const int c0 = cq * 4;
        const float* sbase = (c0 < 64 ? x : tem)
            + ((b * 64 + (c0 & 63)) * Vv + v) * Tt + tl;
        constexpr int CS = Vv * Tt;
        float c0v = sbase[0], c1v = sbase[CS], c2v = sbase[2 * CS], c3v = sbase[3 * CS];
        const int xoff = tl * CIN + ((((c0 >> 3) ^ tl) << 3) + (c0 & 7));

        auto tile_mfma = [&](int tile, int r) {
            const int p = tile >> 2, ot_ = tile & 3;
            f32x4 acc = {0.f, 0.f, 0.f, 0.f};
            const unsigned short* Wb  = ws + p * 8192 + (ot_ * 16 + l15) * CIN + qd * 8;
            const unsigned short* Bbp = xt + l15 * CIN;
            #pragma unroll
            for (int kc = 0; kc < 4; ++kc) {
                bf16x8 a = *(const bf16x8*)(Wb + kc * 32);
                int phys = (kc * 4 + qd) ^ l15;
                bf16x8 bbv = *(const bf16x8*)(Bbp + phys * 8);
                acc = __builtin_amdgcn_mfma_f32_16x16x32_bf16(a, bbv, acc, 0, 0, 0);
            }
            const int obase = ot_ * 16 + qd * 4;
            const float* bp = (p == 0) ? bq : (p == 1 ? bk : bv);
            float4 bias = *(const float4*)(bp + obase);
            float bb4[4] = {bias.x, bias.y, bias.z, bias.w};
            const int tg = r * 16 + l15;
            if (p == 2) {
                // V stored transposed: VT[dg][t], column-swizzled by dg quad-group
                #pragma unroll
                for (int rr = 0; rr < 4; ++rr) {
                    int dg = obase + rr;
                    int tp = tg ^ ((((dg >> 2) & 3)) << 4);
                    vt[dg * 128 + tp] = f2bf(acc[rr] + bb4[rr]);
                }
            } else {
                // Q pre-scaled by log2(e)/sqrt(d); 8B-chunk swizzle ^(t&14)
                float sc = (p == 0) ? QS : 1.0f;
                ushort4 s4;
                s4.x = f2bf((acc[0] + bb4[0]) * sc);
                s4.y = f2bf((acc[1] + bb4[1]) * sc);
                s4.z = f2bf((acc[2] + bb4[2]) * sc);
                s4.w = f2bf((acc[3] + bb4[3]) * sc);
                int phys = (obase >> 2) ^ (tg & 14);
                *(ushort4*)(qk + p * 8192 + tg * 64 + phys * 4) = s4;
            }
        };

        for (int r = 0; r < 8; ++r) {
            if (r) __syncthreads();           // prior round's B-frag reads done
            ushort4 s4;
            s4.x = f2bf(c0v); s4.y = f2bf(c1v); s4.z = f2bf(c2v); s4.w = f2bf(c3v);
            *(ushort4*)(xt + xoff) = s4;
            if (r < 7) {                      // T14: prefetch next round under MFMA+barrier
                int o = (r + 1) * 16;
                c0v = sbase[o];          c1v = sbase[CS + o];
                c2v = sbase[2 * CS + o]; c3v = sbase[3 * CS + o];
            }
            __syncthreads();                  // xt ready
            // 12 tiles (p, ot_) this round; rotation by 4 balances 2-tile waves
            const int wr = (w + ((r & 1) << 2)) & 7;
            tile_mfma(wr, r);
            if (wr < 4) tile_mfma(8 + wr, r);
        }
    }
    __syncthreads();  // Q/K/VT complete

    // ---------------- phase 2: causal attention, wave = head ----------------
    // S^T = K*Q^T via 16x16x16 MFMA (K=8 real, qd<2 lanes carry data).
    // C-layout: col=l15=t, row=qd*4+reg=s. P^T (exp2, masked) feeds PV directly.
    {
        const int h = w;
        // cache V A-frags: lane m=l15=d (valid <8), k=qd*4+j
        short4v vfrag[8];
        {
            const int dg = h * 8 + l15;
            const int swz = ((dg >> 2) & 3) << 4;
            #pragma unroll
            for (int st = 0; st < 8; ++st) {
                short4v f = {0, 0, 0, 0};
                if (l15 < 8) {
                    int sp = (st * 16 + qd * 4) ^ swz;
                    f = *(const short4v*)(vt + dg * 128 + sp);
                }
                vfrag[st] = f;
            }
        }
        __syncthreads();  // all waves' vfrag done; vt region becomes ot

        bool dmask[4];
        #pragma unroll
        for (int r = 0; r < 4; ++r) dmask[r] = (qd * 4 + r) <= l15;  // diag: s<=t
        const int qkoff = ((h * 2 + qd) ^ (l15 & 14)) << 2;  // b64 chunk for qd<2

        for (int tt = 0; tt < 8; ++tt) {
            short4v qf = {0, 0, 0, 0};
            if (qd < 2) qf = *(const short4v*)(qk + (tt * 16 + l15) * 64 + qkoff);
            f32x4 o0 = {0.f, 0.f, 0.f, 0.f}, o1 = {0.f, 0.f, 0.f, 0.f};
            float lac = 0.f;
            #pragma unroll
            for (int st = 0; st < 8; ++st) {
                if (st <= tt) {  // causal tile skip (wave-uniform branch)
                    short4v kf = {0, 0, 0, 0};
                    if (qd < 2) kf = *(const short4v*)(qk + 8192 + (st * 16 + l15) * 64 + qkoff);
                    f32x4 z = {0.f, 0.f, 0.f, 0.f};
                    f32x4 s = MFMA16(kf, qf, z);
                    float p0 = __builtin_amdgcn_exp2f(s[0]);
                    float p1 = __builtin_amdgcn_exp2f(s[1]);
                    float p2 = __builtin_amdgcn_exp2f(s[2]);
                    float p3 = __builtin_amdgcn_exp2f(s[3]);
                    if (st == tt) {  // diagonal tile: per-element causal mask
                        p0 = dmask[0] ? p0 : 0.f;
                        p1 = dmask[1] ? p1 : 0.f;
                        p2 = dmask[2] ? p2 : 0.f;
                        p3 = dmask[3] ? p3 : 0.f;
                    }
                    lac += (p0 + p1) + (p2 + p3);
                    int pp0 = (int)pk2(p0, p1), pp1 = (int)pk2(p2, p3);
                    short4v pf;
                    pf[0] = (short)(pp0 & 0xffff); pf[1] = (short)(pp0 >> 16);
                    pf[2] = (short)(pp1 & 0xffff); pf[3] = (short)(pp1 >> 16);
                    if (st & 1) o1 = MFMA16(vfrag[st], pf, o1);
                    else        o0 = MFMA16(vfrag[st], pf, o0);
                }
            }
            // row sum l(t): partials live at (l15=t, qd); fold quads
            float l = lac;
            l += __shfl_xor(l, 16, 64);
            l += __shfl_xor(l, 32, 64);
            float rl = __builtin_amdgcn_rcpf(l);
            if (qd < 2) {  // O^T rows d=qd*4+reg, only d<8 real
                float r0 = (o0[0] + o1[0]) * rl, r1 = (o0[1] + o1[1]) * rl;
                float r2 = (o0[2] + o1[2]) * rl, r3 = (o0[3] + o1[3]) * rl;
                int t = tt * 16 + l15;
                uint2 st2;
                st2.x = pk2(r0, r1);
                st2.y = pk2(r2, r3);
                *(uint2*)(ot + t * 64 + (((h * 2 + qd) ^ (l15 & 14)) << 2)) = st2;
            }
        }
    }
    __syncthreads();

    // ---------------- phase 3: out-projection via MFMA + bias + relu ----------------
    {
        const int tt = w;  // wave w owns t-tile w
        #pragma unroll
        for (int ot_ = 0; ot_ < 4; ++ot_) {
            f32x4 acc = {0.f, 0.f, 0.f, 0.f};
            const unsigned short* Ab = ws + 24576 + (ot_ * 16 + l15) * COUT + qd * 8;
            #pragma unroll
            for (int kc = 0; kc < 2; ++kc) {
                bf16x8 a = *(const bf16x8*)(Ab + kc * 32);
                bf16x8 bbv = *(const bf16x8*)(ot + (tt * 16 + l15) * 64
                                 + (((kc * 8 + qd * 2) ^ (l15 & 14)) << 2));
                acc = __builtin_amdgcn_mfma_f32_16x16x32_bf16(a, bbv, acc, 0, 0, 0);
            }
            int obase = ot_ * 16 + qd * 4;
            float4 bias = *(const float4*)(bo + obase);
            float bb4[4] = {bias.x, bias.y, bias.z, bias.w};
            int t = tt * 16 + l15;
            #pragma unroll
            for (int r = 0; r < 4; ++r) {
                float val = acc[r] + bb4[r];
                out[((b * COUT + obase + r) * Vv + v) * Tt + t] = val > 0.f ? val : 0.f;
            }
        }
    }
}

extern "C" void kernel_launch(void* const* d_in, const int* in_sizes, int n_in,
                              void* d_out, int out_size, void* d_ws, size_t ws_size,
                              hipStream_t stream) {
    (void)in_sizes; (void)n_in; (void)ws_size; (void)out_size;
    const float* x   = (const float*)d_in[0];
    const float* tem = (const float*)d_in[1];
    const float* Wq  = (const float*)d_in[2];
    const float* bq  = (const float*)d_in[3];
    const float* Wk  = (const float*)d_in[4];
    const float* bk  = (const float*)d_in[5];
    const float* Wv  = (const float*)d_in[6];
    const float* bv  = (const float*)d_in[7];
    const float* Wo  = (const float*)d_in[8];
    const float* bo  = (const float*)d_in[9];
    float* out = (float*)d_out;
    unsigned short* ws = (unsigned short*)d_ws;

    prep_w<<<dim3(112), dim3(256), 0, stream>>>(Wq, Wk, Wv, Wo, ws);
    tatt_fused<<<dim3(Bb * Vv), dim3(TPB), 0, stream>>>(
        x, tem, bq, bk, bv, bo, ws, out);
}

// Round 4
// 224.432 us; speedup vs baseline: 1.2013x; 1.1233x over previous
//
#include <hip/hip_runtime.h>
#include <stdint.h>

#define TPB 512

constexpr int Bb   = 8;    // batch
constexpr int Vv   = 200;  // vertices
constexpr int Tt   = 128;  // time
constexpr int CIN  = 128;  // concat channels
constexpr int COUT = 64;   // K_HEADS * D_HEAD

typedef __attribute__((ext_vector_type(8))) short bf16x8;
typedef __attribute__((ext_vector_type(4))) short short4v;
typedef __attribute__((ext_vector_type(4))) float f32x4;

// bf16 helpers (manual RNE) — verified in R0/R1; do NOT replace with
// v_cvt_pk_bf16_f32 inline asm (R2 produced inf with it).
__device__ __forceinline__ unsigned short f2bf(float f) {
    union { float f; unsigned u; } x; x.f = f;
    unsigned r = x.u + 0x7fffu + ((x.u >> 16) & 1u);
    return (unsigned short)(r >> 16);
}
__device__ __forceinline__ unsigned pk2(float a, float b) {
    return (unsigned)f2bf(a) | ((unsigned)f2bf(b) << 16);
}

// 16x16x16 bf16 MFMA (K=16): used for QK^T (K=8 real) and PV.
#if __has_builtin(__builtin_amdgcn_mfma_f32_16x16x16bf16_1k)
#define MFMA16(a, b, c) __builtin_amdgcn_mfma_f32_16x16x16bf16_1k(a, b, c, 0, 0, 0)
#else
__device__ __forceinline__ f32x4 mfma16_asm(short4v a, short4v b, f32x4 c) {
    f32x4 d;
    asm("v_mfma_f32_16x16x16_bf16 %0, %1, %2, %3" : "=v"(d) : "v"(a), "v"(b), "v"(c));
    return d;
}
#define MFMA16(a, b, c) mfma16_asm(a, b, c)
#endif

// One block per (b, v). LDS 52 KiB -> 3 blocks/CU:
//   qk  bf16 Q[128][64] @0, K[128][64] @16384  (8B-chunk swizzle: phys_hc = hc ^ (t&14))
//   vt  bf16 VT[64 dg][128 s] @32768 (phase 1 + vfrag load)
//   ot  bf16 [128 t][64 i]    @32768 (overlays vt after vfrag barrier)
//   xt  bf16 [16 t][128 c]    @49152 (phase-1 staging, 8 rounds of 16 t)
// W matrices are converted float->bf16 in-register per block (no prep kernel).
__global__ __launch_bounds__(TPB, 6)
void tatt_fused(const float* __restrict__ x, const float* __restrict__ tem,
                const float* __restrict__ Wq, const float* __restrict__ bq,
                const float* __restrict__ Wk, const float* __restrict__ bk,
                const float* __restrict__ Wv, const float* __restrict__ bv,
                const float* __restrict__ Wo, const float* __restrict__ bo,
                float* __restrict__ out)
{
    __shared__ __align__(16) unsigned char smem[53248];
    unsigned short* qk = (unsigned short*)smem;            // Q @0 (elts), K @8192 (elts)
    unsigned short* vt = (unsigned short*)(smem + 32768);  // VT [64][128]
    unsigned short* ot = (unsigned short*)(smem + 32768);  // overlays vt (after barrier)
    unsigned short* xt = (unsigned short*)(smem + 49152);  // [16][128]

    const int tid = threadIdx.x;
    const int w = tid >> 6, lane = tid & 63;
    const int l15 = lane & 15, qd = lane >> 4;
    const int b = blockIdx.x / Vv, v = blockIdx.x % Vv;
    const float QS = 1.44269504088896f * 0.35355339059327f;  // log2(e)/sqrt(8)

    // ---- A-fragment register cache (loaded once per block, from float W) ----
    // waves 0-3: Q tile (p=0, ot_=w) in afr0, K tile (p=1, ot_=w) in afr1
    // waves 4-7: V tile (p=2, ot_=w-4) in afr0
    bf16x8 afr0[4], afr1[4];
    {
        const float* W0 = (w < 4) ? Wq : Wv;
        const int o0_ = (w < 4) ? w : (w - 4);
        const float* base0 = W0 + (o0_ * 16 + l15) * CIN + qd * 8;
        #pragma unroll
        for (int kc = 0; kc < 4; ++kc) {
            float4 fa = *(const float4*)(base0 + kc * 32);
            float4 fb = *(const float4*)(base0 + kc * 32 + 4);
            union { bf16x8 v8; unsigned u[4]; } t;
            t.u[0] = pk2(fa.x, fa.y); t.u[1] = pk2(fa.z, fa.w);
            t.u[2] = pk2(fb.x, fb.y); t.u[3] = pk2(fb.z, fb.w);
            afr0[kc] = t.v8;
        }
        if (w < 4) {
            const float* base1 = Wk + (w * 16 + l15) * CIN + qd * 8;
            #pragma unroll
            for (int kc = 0; kc < 4; ++kc) {
                float4 fa = *(const float4*)(base1 + kc * 32);
                float4 fb = *(const float4*)(base1 + kc * 32 + 4);
                union { bf16x8 v8; unsigned u[4]; } t;
                t.u[0] = pk2(fa.x, fa.y); t.u[1] = pk2(fa.z, fa.w);
                t.u[2] = pk2(fb.x, fb.y); t.u[3] = pk2(fb.z, fb.w);
                afr1[kc] = t.v8;
            }
        }
    }

    // one 16x16 projection tile: C = A(W) * B(xt), bias, store to Q/K/V LDS
    auto tileC = [&](const bf16x8 (&A)[4], int p, int ot_, int r) {
        f32x4 acc = {0.f, 0.f, 0.f, 0.f};
        const unsigned short* Bbp = xt + l15 * CIN;
        #pragma unroll
        for (int kc = 0; kc < 4; ++kc) {
            int phys = (kc * 4 + qd) ^ l15;
            bf16x8 bb = *(const bf16x8*)(Bbp + phys * 8);
            acc = __builtin_amdgcn_mfma_f32_16x16x32_bf16(A[kc], bb, acc, 0, 0, 0);
        }
        const int obase = ot_ * 16 + qd * 4;
        const float* bp = (p == 0) ? bq : ((p == 1) ? bk : bv);
        float4 bias = *(const float4*)(bp + obase);
        float bb4[4] = {bias.x, bias.y, bias.z, bias.w};
        const int tg = r * 16 + l15;
        if (p == 2) {
            // V stored transposed: VT[dg][t], column-swizzled by dg quad-group
            #pragma unroll
            for (int rr = 0; rr < 4; ++rr) {
                int dg = obase + rr;
                int tp = tg ^ ((((dg >> 2) & 3)) << 4);
                vt[dg * 128 + tp] = f2bf(acc[rr] + bb4[rr]);
            }
        } else {
            // Q pre-scaled by log2(e)/sqrt(d); 8B-chunk swizzle ^(t&14)
            float sc = (p == 0) ? QS : 1.0f;
            ushort4 s4;
            s4.x = f2bf((acc[0] + bb4[0]) * sc);
            s4.y = f2bf((acc[1] + bb4[1]) * sc);
            s4.z = f2bf((acc[2] + bb4[2]) * sc);
            s4.w = f2bf((acc[3] + bb4[3]) * sc);
            int phys = (obase >> 2) ^ (tg & 14);
            *(ushort4*)(qk + p * 8192 + tg * 64 + phys * 4) = s4;
        }
    };

    // ---------------- phase 1: QKV projection, 8 rounds of 16 t ----------------
    {
        // staging: thread owns (1 channel, 4 consecutive t) -> one float4 load
        const int sc_ = tid >> 2;   // channel 0..127
        const int stq = tid & 3;    // t-quad
        const float* sbase = (sc_ < 64 ? x : tem)
            + ((b * 64 + (sc_ & 63)) * Vv + v) * Tt + stq * 4;
        float4 pf = *(const float4*)(sbase);
        const int clow = sc_ & 7, chi = sc_ >> 3;

        for (int r = 0; r < 8; ++r) {
            if (r) __syncthreads();           // prior round's B-frag reads done
            {
                int t0 = stq * 4;
                xt[(t0 + 0) * CIN + ((chi ^ (t0 + 0)) << 3) + clow] = f2bf(pf.x);
                xt[(t0 + 1) * CIN + ((chi ^ (t0 + 1)) << 3) + clow] = f2bf(pf.y);
                xt[(t0 + 2) * CIN + ((chi ^ (t0 + 2)) << 3) + clow] = f2bf(pf.z);
                xt[(t0 + 3) * CIN + ((chi ^ (t0 + 3)) << 3) + clow] = f2bf(pf.w);
            }
            if (r < 7) pf = *(const float4*)(sbase + (r + 1) * 16);  // T14 prefetch
            __syncthreads();                  // xt ready
            if (w < 4) { tileC(afr0, 0, w, r); tileC(afr1, 1, w, r); }
            else       { tileC(afr0, 2, w - 4, r); }
        }
    }
    __syncthreads();  // Q/K/VT complete

    // ---------------- phase 2: causal attention, wave = head ----------------
    // S^T = K*Q^T via 16x16x16 MFMA (K=8 real, qd<2 lanes carry data).
    // C-layout: col=l15=t, row=qd*4+reg=s. P^T (exp2, masked) feeds PV directly.
    {
        const int h = w;
        // cache V A-frags: lane m=l15=d (valid <8), k=qd*4+j
        short4v vfrag[8];
        {
            const int dg = h * 8 + l15;
            const int swz = ((dg >> 2) & 3) << 4;
            #pragma unroll
            for (int st = 0; st < 8; ++st) {
                short4v f = {0, 0, 0, 0};
                if (l15 < 8) {
                    int sp = (st * 16 + qd * 4) ^ swz;
                    f = *(const short4v*)(vt + dg * 128 + sp);
                }
                vfrag[st] = f;
            }
        }
        __syncthreads();  // all waves' vfrag done; vt region becomes ot

        bool dmask[4];
        #pragma unroll
        for (int r = 0; r < 4; ++r) dmask[r] = (qd * 4 + r) <= l15;  // diag: s<=t
        const int qkoff = ((h * 2 + qd) ^ (l15 & 14)) << 2;  // b64 chunk for qd<2

        #pragma unroll
        for (int tt = 0; tt < 8; ++tt) {
            short4v qf = {0, 0, 0, 0};
            if (qd < 2) qf = *(const short4v*)(qk + (tt * 16 + l15) * 64 + qkoff);
            f32x4 o0 = {0.f, 0.f, 0.f, 0.f}, o1 = {0.f, 0.f, 0.f, 0.f};
            float lac = 0.f;
            #pragma unroll
            for (int st = 0; st < 8; ++st) {
                if (st <= tt) {  // compile-time pruned (full unroll)
                    short4v kf = {0, 0, 0, 0};
                    if (qd < 2) kf = *(const short4v*)(qk + 8192 + (st * 16 + l15) * 64 + qkoff);
                    f32x4 z = {0.f, 0.f, 0.f, 0.f};
                    f32x4 s = MFMA16(kf, qf, z);
                    float p0 = __builtin_amdgcn_exp2f(s[0]);
                    float p1 = __builtin_amdgcn_exp2f(s[1]);
                    float p2 = __builtin_amdgcn_exp2f(s[2]);
                    float p3 = __builtin_amdgcn_exp2f(s[3]);
                    if (st == tt) {  // diagonal tile: per-element causal mask
                        p0 = dmask[0] ? p0 : 0.f;
                        p1 = dmask[1] ? p1 : 0.f;
                        p2 = dmask[2] ? p2 : 0.f;
                        p3 = dmask[3] ? p3 : 0.f;
                    }
                    lac += (p0 + p1) + (p2 + p3);
                    int pp0 = (int)pk2(p0, p1), pp1 = (int)pk2(p2, p3);
                    short4v pf;
                    pf[0] = (short)(pp0 & 0xffff); pf[1] = (short)(pp0 >> 16);
                    pf[2] = (short)(pp1 & 0xffff); pf[3] = (short)(pp1 >> 16);
                    if (st & 1) o1 = MFMA16(vfrag[st], pf, o1);
                    else        o0 = MFMA16(vfrag[st], pf, o0);
                }
            }
            // row sum l(t): partials live at (l15=t, qd); fold quads
            float l = lac;
            l += __shfl_xor(l, 16, 64);
            l += __shfl_xor(l, 32, 64);
            float rl = __builtin_amdgcn_rcpf(l);
            if (qd < 2) {  // O^T rows d=qd*4+reg, only d<8 real
                float r0 = (o0[0] + o1[0]) * rl, r1 = (o0[1] + o1[1]) * rl;
                float r2 = (o0[2] + o1[2]) * rl, r3 = (o0[3] + o1[3]) * rl;
                int t = tt * 16 + l15;
                uint2 st2;
                st2.x = pk2(r0, r1);
                st2.y = pk2(r2, r3);
                *(uint2*)(ot + t * 64 + (((h * 2 + qd) ^ (l15 & 14)) << 2)) = st2;
            }
        }
    }
    __syncthreads();

    // ---------------- phase 3: out-projection + bias + relu ----------------
    // wave w: t-tiles {2(w&3), 2(w&3)+1} x ot_ {2(w>>2), 2(w>>2)+1} ->
    // each channel row's full 128B line written by ONE wave (no HBM RMW).
    {
        const int tq3 = w & 3, ohB = (w >> 2) * 2;
        bf16x8 wof[2][2];
        #pragma unroll
        for (int oth = 0; oth < 2; ++oth) {
            const float* base = Wo + ((ohB + oth) * 16 + l15) * COUT + qd * 8;
            #pragma unroll
            for (int kc = 0; kc < 2; ++kc) {
                float4 fa = *(const float4*)(base + kc * 32);
                float4 fb = *(const float4*)(base + kc * 32 + 4);
                union { bf16x8 v8; unsigned u[4]; } t;
                t.u[0] = pk2(fa.x, fa.y); t.u[1] = pk2(fa.z, fa.w);
                t.u[2] = pk2(fb.x, fb.y); t.u[3] = pk2(fb.z, fb.w);
                wof[oth][kc] = t.v8;
            }
        }
        #pragma unroll
        for (int ts = 0; ts < 2; ++ts) {
            const int tt = tq3 * 2 + ts;
            #pragma unroll
            for (int oth = 0; oth < 2; ++oth) {
                const int ot_ = ohB + oth;
                f32x4 acc = {0.f, 0.f, 0.f, 0.f};
                #pragma unroll
                for (int kc = 0; kc < 2; ++kc) {
                    bf16x8 bb = *(const bf16x8*)(ot + (tt * 16 + l15) * 64
                                     + (((kc * 8 + qd * 2) ^ (l15 & 14)) << 2));
                    acc = __builtin_amdgcn_mfma_f32_16x16x32_bf16(wof[oth][kc], bb, acc, 0, 0, 0);
                }
                const int obase = ot_ * 16 + qd * 4;
                float4 bias = *(const float4*)(bo + obase);
                const int t = tt * 16 + l15;
                float vr[4] = {acc[0] + bias.x, acc[1] + bias.y,
                               acc[2] + bias.z, acc[3] + bias.w};
                #pragma unroll
                for (int r = 0; r < 4; ++r) {
                    float val = vr[r];
                    out[((b * COUT + obase + r) * Vv + v) * Tt + t] = val > 0.f ? val : 0.f;
                }
            }
        }
    }
}

extern "C" void kernel_launch(void* const* d_in, const int* in_sizes, int n_in,
                              void* d_out, int out_size, void* d_ws, size_t ws_size,
                              hipStream_t stream) {
    (void)in_sizes; (void)n_in; (void)ws_size; (void)out_size; (void)d_ws;
    const float* x   = (const float*)d_in[0];
    const float* tem = (const float*)d_in[1];
    const float* Wq  = (const float*)d_in[2];
    const float* bq  = (const float*)d_in[3];
    const float* Wk  = (const float*)d_in[4];
    const float* bk  = (const float*)d_in[5];
    const float* Wv  = (const float*)d_in[6];
    const float* bv  = (const float*)d_in[7];
    const float* Wo  = (const float*)d_in[8];
    const float* bo  = (const float*)d_in[9];
    float* out = (float*)d_out;

    tatt_fused<<<dim3(Bb * Vv), dim3(TPB), 0, stream>>>(
        x, tem, Wq, bq, Wk, bk, Wv, bv, Wo, bo, out);
}